// Round 11
// baseline (241.262 us; speedup 1.0000x reference)
//
#include <hip/hip_runtime.h>
#include <hip/hip_bf16.h>

// CIN forward: 3 chained GEMMs M=16384, N=256, K={1600,5120,5120}, bf16 MFMA.
// A rows are outer products h_r (x) x_r formed in registers.
// Global K-permutation: k' = s*32 + q*8 + j  <->  f = 4*(s%SPW)+q, g = 8*(s/SPW)+j
// applied identically to A-formation and the pre-fragmented W blob (layout-immune).
// K-loop: R4's proven 4-slot LDS pipeline, 3-deep global_load_lds prefetch,
// counted s_waitcnt vmcnt(2) + raw s_barrier.
// R7 vs R4: (a) A-pack via manual RNE bit-trick (pkrne; NaN-free data) --
//   NOT v_cvt_pk_bf16_f32 asm, which mis-rounds (R6 A/B: absmax 2.31 vs 0.125);
// (b) A-formation software-pipelined one K-step ahead: A depends only on
//   h/x LDS (written once in prologue), so form A(s+1) overlaps MFMA(s).
// (R7/R8/R9/R10 benches were infra timeouts; identical resubmit.)

typedef __attribute__((ext_vector_type(8))) short short8;
typedef __attribute__((ext_vector_type(4))) float f32x4;

#define DEVINL __device__ __forceinline__

DEVINL float bf16f(unsigned short u) {
  return __builtin_bit_cast(float, ((unsigned int)u) << 16);
}
DEVINL unsigned short f2bf(float f) {
  unsigned int u = __builtin_bit_cast(unsigned int, f);
  u = u + 0x7FFFu + ((u >> 16) & 1u);
  return (unsigned short)(u >> 16);
}
DEVINL unsigned int pk2(float lo, float hi) {
  union { __hip_bfloat162 h; unsigned int u; } cv;
  cv.h = __float22bfloat162_rn(make_float2(lo, hi));
  return cv.u;
}
// RNE f32->bf16 pair pack, no NaN handling (data is NaN-free). Bit-identical
// to __float22bfloat162_rn for finite values; ~half the instructions.
DEVINL unsigned int pkrne(float a, float b) {
  unsigned int ua = __builtin_bit_cast(unsigned int, a);
  unsigned int ub = __builtin_bit_cast(unsigned int, b);
  ua = ua + 0x7FFFu + ((ua >> 16) & 1u);
  ub = ub + 0x7FFFu + ((ub >> 16) & 1u);
  return (ua >> 16) | (ub & 0xFFFF0000u);
}
DEVINL void gl_lds16(const unsigned short* g, unsigned short* l) {
  __builtin_amdgcn_global_load_lds(
      (const __attribute__((address_space(1))) unsigned int*)g,
      (__attribute__((address_space(3))) unsigned int*)l, 16, 0, 0);
}

// ---------------- prep: x transpose  in[b][g][d] f32 -> xT[(b*32+d)][g] bf16
__global__ void prep_x(const float* __restrict__ in, unsigned short* __restrict__ xT) {
  __shared__ float lf[40 * 33];
  const int b = blockIdx.x, t = threadIdx.x;
  for (int i = t; i < 1280; i += 256) {
    int g = i >> 5, d = i & 31;
    lf[g * 33 + d] = in[b * 1280 + i];
  }
  __syncthreads();
  for (int i = t; i < 1280; i += 256) {
    int d = i / 40, g = i % 40;
    xT[b * 1280 + i] = f2bf(lf[g * 33 + d]);
  }
}

// ---------------- prep: fragment weights with the global K-permutation.
// blob: [s][grp 0..15][lane 0..63][j 0..7], value = W[f*40+g][grp*16+(lane&15)]
// with f = 4*(s%SPW) + (lane>>4), g = 8*(s/SPW) + j.
__global__ void prep_w(const float* __restrict__ W1, const float* __restrict__ W2,
                       const float* __restrict__ W3, unsigned short* __restrict__ Wf1,
                       unsigned short* __restrict__ Wf2, unsigned short* __restrict__ Wf3) {
  __shared__ float lw[8192];
  const int bid = blockIdx.x, t = threadIdx.x;
  const float* W; unsigned short* dst; int s, SPW;
  if (bid < 50)       { W = W1; dst = Wf1; s = bid;       SPW = 10; }
  else if (bid < 210) { W = W2; dst = Wf2; s = bid - 50;  SPW = 32; }
  else                { W = W3; dst = Wf3; s = bid - 210; SPW = 32; }
  const int smod = s % SPW, w = s / SPW;
  for (int i = t; i < 8192; i += 256) {
    int kl = i >> 8, col = i & 255;
    int f = 4 * smod + (kl >> 3);
    int g = 8 * w + (kl & 7);
    lw[i] = W[(f * 40 + g) * 256 + col];
  }
  __syncthreads();
  for (int c = t; c < 1024; c += 256) {
    int grp = c >> 6, ll = c & 63;
    int qq = ll >> 4, col = grp * 16 + (ll & 15);
    unsigned short u[8];
#pragma unroll
    for (int j = 0; j < 8; ++j) u[j] = f2bf(lw[(qq * 8 + j) * 256 + col]);
    uint4 v;
    v.x = (unsigned)u[0] | ((unsigned)u[1] << 16);
    v.y = (unsigned)u[2] | ((unsigned)u[3] << 16);
    v.z = (unsigned)u[4] | ((unsigned)u[5] << 16);
    v.w = (unsigned)u[6] | ((unsigned)u[7] << 16);
    *(uint4*)&dst[s * 8192 + c * 8] = v;
  }
}

// ---------------- main layer kernel
// grid 512: blockIdx = bm*4 + tn.  BM=128 rows, BN=64 cols (quarter of N=256).
// 4 waves, all in M: wave tile 32x64 (m-iters=2, n-iters=4), 16x16x32 bf16 MFMA.
template <int LAYER>
__global__ __launch_bounds__(256, 2) void cin_layer(
    const unsigned short* __restrict__ Wfrag, const unsigned short* __restrict__ xT,
    const unsigned short* __restrict__ hIn, const float* __restrict__ bias,
    unsigned short* __restrict__ hOut, float* __restrict__ out) {
  constexpr int FIN = (LAYER == 1) ? 40 : 128;
  constexpr int NKT = FIN * 40 / 32;   // 50 / 160
  constexpr int SPW = FIN / 4;         // 10 / 32 (steps per g-window)
  constexpr int HP = 144;              // h row pitch (shorts)

  // LDS: Bb[4][2048] quad-buffered B | xs[128][40] | (L>1) hs[128 f][HP]
  constexpr int SM_SHORTS = 8192 + 5120 + ((LAYER > 1) ? 128 * HP : 8);
  __shared__ __align__(16) unsigned short smem[SM_SHORTS];
  unsigned short* Bb = smem;
  unsigned short* xs = smem + 8192;
  unsigned short* hs = smem + 8192 + 5120;

  const int tid = threadIdx.x;
  const int l = tid & 63;
  const int wid = tid >> 6;
  const int q = l >> 4;
  const int bm = blockIdx.x >> 2;
  const int tn = blockIdx.x & 3;
  const int r0 = bm * 128;
  const int b0 = bm * 4;

  // ---- prologue staging (all global_load_lds, fully drained at syncthreads)
#pragma unroll
  for (int s = 0; s < 3; ++s)
    gl_lds16(Wfrag + s * 8192 + tn * 2048 + tid * 8, Bb + s * 2048 + tid * 8);
  // xs = 5120 shorts = 2.5 stage rounds (exact; NO overflow)
  gl_lds16(xT + r0 * 40 + tid * 8, xs + tid * 8);
  gl_lds16(xT + r0 * 40 + 2048 + tid * 8, xs + 2048 + tid * 8);
  if (tid < 128)
    gl_lds16(xT + r0 * 40 + 4096 + tid * 8, xs + 4096 + tid * 8);
  if constexpr (LAYER > 1) {
    const unsigned short* hsrc = hIn + bm * (128 * HP);
#pragma unroll
    for (int i = 0; i < 9; ++i)   // 9*4096B = 36864B = 128*HP shorts exactly
      gl_lds16(hsrc + i * 2048 + tid * 8, hs + i * 2048 + tid * 8);
  }

  f32x4 acc[2][4];
#pragma unroll
  for (int m = 0; m < 2; ++m)
#pragma unroll
    for (int n = 0; n < 4; ++n) acc[m][n] = f32x4{0.f, 0.f, 0.f, 0.f};

  const int rl0 = wid * 32 + (l & 15);       // mi=0 row; mi=1 adds 16

  __syncthreads();   // full drain once (prologue loads + barrier)

  union AU { unsigned int u[4]; short8 s8; };

#pragma unroll
  for (int w = 0; w < 5; ++w) {
    // expand this g-window of x to f32 registers (static indices)
    float xw[2][8];
#pragma unroll
    for (int mi = 0; mi < 2; ++mi) {
      short8 xv = *(const short8*)&xs[(rl0 + mi * 16) * 40 + w * 8];
#pragma unroll
      for (int d = 0; d < 4; ++d) {
        unsigned int uu = ((const unsigned int*)&xv)[d];
        xw[mi][2 * d]     = __builtin_bit_cast(float, uu << 16);
        xw[mi][2 * d + 1] = __builtin_bit_cast(float, uu & 0xffff0000u);
      }
    }

    // form A for sm=0 of this window (f = q)
    AU Apre[2];
#pragma unroll
    for (int mi = 0; mi < 2; ++mi) {
      const int rl = rl0 + mi * 16;
      const float hf = (LAYER == 1) ? bf16f(xs[rl * 40 + q])
                                    : bf16f(hs[q * HP + rl]);
#pragma unroll
      for (int jj = 0; jj < 4; ++jj)
        Apre[mi].u[jj] = pkrne(hf * xw[mi][2 * jj], hf * xw[mi][2 * jj + 1]);
    }

    for (int sm = 0; sm < SPW; ++sm) {
      const int s = w * SPW + sm;
      __builtin_amdgcn_sched_barrier(0);
      asm volatile("s_waitcnt vmcnt(2)" ::: "memory");
      __builtin_amdgcn_s_barrier();
      __builtin_amdgcn_sched_barrier(0);

      // stage s+3 (clamped: tail stages are redundant writes to consumed slots)
      const int sn = (s + 3 < NKT) ? (s + 3) : (NKT - 1);
      gl_lds16(Wfrag + sn * 8192 + tn * 2048 + tid * 8,
               Bb + ((s + 3) & 3) * 2048 + tid * 8);

      // B fragments for this step
      const unsigned short* bb = Bb + (s & 3) * 2048;
      short8 bfr[4];
#pragma unroll
      for (int n = 0; n < 4; ++n)
        bfr[n] = *(const short8*)&bb[n * 512 + l * 8];

      // lookahead: form A for sm+1 (clamped at window end; h/x LDS is
      // prologue-written and never rewritten, so no barrier hazard)
      const int smn = (sm + 1 < SPW) ? sm + 1 : SPW - 1;
      const int fn = 4 * smn + q;
      AU Anxt[2];
#pragma unroll
      for (int mi = 0; mi < 2; ++mi) {
        const int rl = rl0 + mi * 16;
        const float hf = (LAYER == 1) ? bf16f(xs[rl * 40 + fn])
                                      : bf16f(hs[fn * HP + rl]);
#pragma unroll
        for (int jj = 0; jj < 4; ++jj)
          Anxt[mi].u[jj] = pkrne(hf * xw[mi][2 * jj], hf * xw[mi][2 * jj + 1]);
      }

      // MFMA with pre-formed A
#pragma unroll
      for (int mi = 0; mi < 2; ++mi)
#pragma unroll
        for (int n = 0; n < 4; ++n)
          acc[mi][n] = __builtin_amdgcn_mfma_f32_16x16x32_bf16(
              Apre[mi].s8, bfr[n], acc[mi][n], 0, 0, 0);

      Apre[0] = Anxt[0];
      Apre[1] = Anxt[1];
    }
  }
  asm volatile("s_waitcnt vmcnt(0)" ::: "memory");

  // ---- epilogue
  const int colb = tn * 64;
  float bv[4];
#pragma unroll
  for (int n = 0; n < 4; ++n) bv[n] = bias[colb + n * 16 + (l & 15)];

  if (LAYER == 3 || tn < 2) {
    const int jb = (LAYER == 1) ? 0 : (LAYER == 2) ? 128 : 256;
#pragma unroll
    for (int n = 0; n < 4; ++n) {
      const int j = jb + colb + n * 16 + (l & 15);
      float sum = 0.f;
#pragma unroll
      for (int m = 0; m < 2; ++m)
#pragma unroll
        for (int r = 0; r < 4; ++r) sum += fmaxf(acc[m][n][r] + bv[n], 0.f);
      sum += __shfl_xor(sum, 16);
      sum += __shfl_xor(sum, 32);
      if (l < 16) out[(b0 + wid) * 512 + j] = sum;
    }
  } else {
    // h half: cols 128..255 -> hOut[bm][f][rl], pitch 144
#pragma unroll
    for (int n = 0; n < 4; ++n) {
      const int ff = (tn - 2) * 64 + n * 16 + (l & 15);
#pragma unroll
      for (int m = 0; m < 2; ++m) {
        const int rl = wid * 32 + m * 16 + (l >> 4) * 4;
        float v0 = fmaxf(acc[m][n][0] + bv[n], 0.f);
        float v1 = fmaxf(acc[m][n][1] + bv[n], 0.f);
        float v2 = fmaxf(acc[m][n][2] + bv[n], 0.f);
        float v3 = fmaxf(acc[m][n][3] + bv[n], 0.f);
        uint2 pv;
        pv.x = pk2(v0, v1);
        pv.y = pk2(v2, v3);
        *(uint2*)&hOut[bm * (128 * HP) + ff * HP + rl] = pv;
      }
    }
  }
}

extern "C" void kernel_launch(void* const* d_in, const int* in_sizes, int n_in,
                              void* d_out, int out_size, void* d_ws, size_t ws_size,
                              hipStream_t stream) {
  (void)in_sizes; (void)n_in; (void)out_size; (void)ws_size;
  const float* in = (const float*)d_in[0];
  const float* W1 = (const float*)d_in[1];
  const float* b1 = (const float*)d_in[2];
  const float* W2 = (const float*)d_in[3];
  const float* b2 = (const float*)d_in[4];
  const float* W3 = (const float*)d_in[5];
  const float* b3 = (const float*)d_in[6];
  float* out = (float*)d_out;
  char* ws = (char*)d_ws;

  unsigned short* xT  = (unsigned short*)(ws);                 // 1,310,720 B
  unsigned short* Wf1 = (unsigned short*)(ws + 1310720);       //   819,200 B
  unsigned short* Wf2 = (unsigned short*)(ws + 2129920);       // 2,621,440 B
  unsigned short* Wf3 = (unsigned short*)(ws + 4751360);       // 2,621,440 B
  unsigned short* h1  = (unsigned short*)(ws + 7372800);       // 4,718,592 B
  unsigned short* h2  = (unsigned short*)(ws + 12091392);      // 4,718,592 B

  prep_x<<<dim3(512), dim3(256), 0, stream>>>(in, xT);
  prep_w<<<dim3(370), dim3(256), 0, stream>>>(W1, W2, W3, Wf1, Wf2, Wf3);
  cin_layer<1><<<dim3(512), dim3(256), 0, stream>>>(Wf1, xT, (const unsigned short*)nullptr, b1, h1, out);
  cin_layer<2><<<dim3(512), dim3(256), 0, stream>>>(Wf2, xT, h1, b2, h2, out);
  cin_layer<3><<<dim3(512), dim3(256), 0, stream>>>(Wf3, xT, h2, b3, (unsigned short*)nullptr, out);
}

// Round 12
// 200.646 us; speedup vs baseline: 1.2024x; 1.2024x over previous
//
#include <hip/hip_runtime.h>
#include <hip/hip_bf16.h>

// CIN forward: 3 chained GEMMs M=16384, N=256, K={1600,5120,5120}, bf16 MFMA.
// A rows are outer products h_r (x) x_r formed in registers.
// Global K-permutation: k' = s*32 + q*8 + j  <->  f = 4*(s%SPW)+q, g = 8*(s/SPW)+j
// applied identically to A-formation and the pre-fragmented W blob (layout-immune).
// R12 vs R4 (single structural change): 8-slot LDS pipeline (slot = s&7),
// PHASE = 2 K-steps per barrier, stage steps s+4/s+5 each phase, counted
// s_waitcnt vmcnt(2). Compute is exactly R4's (pk2 pack; no pkrne, no
// lookahead -- R11 A/B showed that combo regressed 63->86us).

typedef __attribute__((ext_vector_type(8))) short short8;
typedef __attribute__((ext_vector_type(4))) float f32x4;

#define DEVINL __device__ __forceinline__

DEVINL float bf16f(unsigned short u) {
  return __builtin_bit_cast(float, ((unsigned int)u) << 16);
}
DEVINL unsigned short f2bf(float f) {
  unsigned int u = __builtin_bit_cast(unsigned int, f);
  u = u + 0x7FFFu + ((u >> 16) & 1u);
  return (unsigned short)(u >> 16);
}
DEVINL unsigned int pk2(float lo, float hi) {
  union { __hip_bfloat162 h; unsigned int u; } cv;
  cv.h = __float22bfloat162_rn(make_float2(lo, hi));
  return cv.u;
}
DEVINL void gl_lds16(const unsigned short* g, unsigned short* l) {
  __builtin_amdgcn_global_load_lds(
      (const __attribute__((address_space(1))) unsigned int*)g,
      (__attribute__((address_space(3))) unsigned int*)l, 16, 0, 0);
}

// ---------------- prep: x transpose  in[b][g][d] f32 -> xT[(b*32+d)][g] bf16
__global__ void prep_x(const float* __restrict__ in, unsigned short* __restrict__ xT) {
  __shared__ float lf[40 * 33];
  const int b = blockIdx.x, t = threadIdx.x;
  for (int i = t; i < 1280; i += 256) {
    int g = i >> 5, d = i & 31;
    lf[g * 33 + d] = in[b * 1280 + i];
  }
  __syncthreads();
  for (int i = t; i < 1280; i += 256) {
    int d = i / 40, g = i % 40;
    xT[b * 1280 + i] = f2bf(lf[g * 33 + d]);
  }
}

// ---------------- prep: fragment weights with the global K-permutation.
// blob: [s][grp 0..15][lane 0..63][j 0..7], value = W[f*40+g][grp*16+(lane&15)]
// with f = 4*(s%SPW) + (lane>>4), g = 8*(s/SPW) + j.
__global__ void prep_w(const float* __restrict__ W1, const float* __restrict__ W2,
                       const float* __restrict__ W3, unsigned short* __restrict__ Wf1,
                       unsigned short* __restrict__ Wf2, unsigned short* __restrict__ Wf3) {
  __shared__ float lw[8192];
  const int bid = blockIdx.x, t = threadIdx.x;
  const float* W; unsigned short* dst; int s, SPW;
  if (bid < 50)       { W = W1; dst = Wf1; s = bid;       SPW = 10; }
  else if (bid < 210) { W = W2; dst = Wf2; s = bid - 50;  SPW = 32; }
  else                { W = W3; dst = Wf3; s = bid - 210; SPW = 32; }
  const int smod = s % SPW, w = s / SPW;
  for (int i = t; i < 8192; i += 256) {
    int kl = i >> 8, col = i & 255;
    int f = 4 * smod + (kl >> 3);
    int g = 8 * w + (kl & 7);
    lw[i] = W[(f * 40 + g) * 256 + col];
  }
  __syncthreads();
  for (int c = t; c < 1024; c += 256) {
    int grp = c >> 6, ll = c & 63;
    int qq = ll >> 4, col = grp * 16 + (ll & 15);
    unsigned short u[8];
#pragma unroll
    for (int j = 0; j < 8; ++j) u[j] = f2bf(lw[(qq * 8 + j) * 256 + col]);
    uint4 v;
    v.x = (unsigned)u[0] | ((unsigned)u[1] << 16);
    v.y = (unsigned)u[2] | ((unsigned)u[3] << 16);
    v.z = (unsigned)u[4] | ((unsigned)u[5] << 16);
    v.w = (unsigned)u[6] | ((unsigned)u[7] << 16);
    *(uint4*)&dst[s * 8192 + c * 8] = v;
  }
}

// ---------------- main layer kernel
// grid 512: blockIdx = bm*4 + tn.  BM=128 rows, BN=64 cols (quarter of N=256).
// 4 waves, all in M: wave tile 32x64 (m-iters=2, n-iters=4), 16x16x32 bf16 MFMA.
template <int LAYER>
__global__ __launch_bounds__(256, 2) void cin_layer(
    const unsigned short* __restrict__ Wfrag, const unsigned short* __restrict__ xT,
    const unsigned short* __restrict__ hIn, const float* __restrict__ bias,
    unsigned short* __restrict__ hOut, float* __restrict__ out) {
  constexpr int FIN = (LAYER == 1) ? 40 : 128;
  constexpr int NKT = FIN * 40 / 32;   // 50 / 160
  constexpr int SPW = FIN / 4;         // 10 / 32 (steps per g-window); even
  constexpr int HP = 144;              // h row pitch (shorts)

  // LDS: Bb[8][2048] eight-slot B pipeline | xs[128][40] | (L>1) hs[128 f][HP]
  constexpr int SM_SHORTS = 16384 + 5120 + ((LAYER > 1) ? 128 * HP : 8);
  __shared__ __align__(16) unsigned short smem[SM_SHORTS];
  unsigned short* Bb = smem;
  unsigned short* xs = smem + 16384;
  unsigned short* hs = smem + 16384 + 5120;

  const int tid = threadIdx.x;
  const int l = tid & 63;
  const int wid = tid >> 6;
  const int q = l >> 4;
  const int bm = blockIdx.x >> 2;
  const int tn = blockIdx.x & 3;
  const int r0 = bm * 128;
  const int b0 = bm * 4;

  const unsigned short* Wbase = Wfrag + tn * 2048 + tid * 8;

  // ---- prologue staging (all global_load_lds, fully drained at syncthreads)
  // steps 0..3 -> slots 0..3
#pragma unroll
  for (int s = 0; s < 4; ++s)
    gl_lds16(Wbase + s * 8192, Bb + s * 2048 + tid * 8);
  // xs = 5120 shorts = 2.5 stage rounds (exact; NO overflow)
  gl_lds16(xT + r0 * 40 + tid * 8, xs + tid * 8);
  gl_lds16(xT + r0 * 40 + 2048 + tid * 8, xs + 2048 + tid * 8);
  if (tid < 128)
    gl_lds16(xT + r0 * 40 + 4096 + tid * 8, xs + 4096 + tid * 8);
  if constexpr (LAYER > 1) {
    const unsigned short* hsrc = hIn + bm * (128 * HP);
#pragma unroll
    for (int i = 0; i < 9; ++i)   // 9*4096B = 36864B = 128*HP shorts exactly
      gl_lds16(hsrc + i * 2048 + tid * 8, hs + i * 2048 + tid * 8);
  }

  f32x4 acc[2][4];
#pragma unroll
  for (int m = 0; m < 2; ++m)
#pragma unroll
    for (int n = 0; n < 4; ++n) acc[m][n] = f32x4{0.f, 0.f, 0.f, 0.f};

  const int rl0 = wid * 32 + (l & 15);       // mi=0 row; mi=1 adds 16

  __syncthreads();   // full drain once (prologue loads + barrier)

#pragma unroll
  for (int w = 0; w < 5; ++w) {
    // expand this g-window of x to f32 registers (static indices)
    float xw[2][8];
#pragma unroll
    for (int mi = 0; mi < 2; ++mi) {
      short8 xv = *(const short8*)&xs[(rl0 + mi * 16) * 40 + w * 8];
#pragma unroll
      for (int d = 0; d < 4; ++d) {
        unsigned int uu = ((const unsigned int*)&xv)[d];
        xw[mi][2 * d]     = __builtin_bit_cast(float, uu << 16);
        xw[mi][2 * d + 1] = __builtin_bit_cast(float, uu & 0xffff0000u);
      }
    }

    for (int sp = 0; sp < SPW / 2; ++sp) {
      const int s0 = w * SPW + 2 * sp;     // phase covers steps s0, s0+1
      __builtin_amdgcn_sched_barrier(0);
      asm volatile("s_waitcnt vmcnt(2)" ::: "memory");
      __builtin_amdgcn_s_barrier();
      __builtin_amdgcn_sched_barrier(0);

      // stage steps s0+4, s0+5 (clamped; tail stages land in dead slots)
      {
        const int sn0 = (s0 + 4 < NKT) ? (s0 + 4) : (NKT - 1);
        const int sn1 = (s0 + 5 < NKT) ? (s0 + 5) : (NKT - 1);
        gl_lds16(Wbase + sn0 * 8192, Bb + ((s0 + 4) & 7) * 2048 + tid * 8);
        gl_lds16(Wbase + sn1 * 8192, Bb + ((s0 + 5) & 7) * 2048 + tid * 8);
      }

      // two K-steps, no barrier between them (compiler may interleave)
#pragma unroll
      for (int half = 0; half < 2; ++half) {
        const int s = s0 + half;
        const int sm = 2 * sp + half;
        const unsigned short* bb = Bb + (s & 7) * 2048 + l * 8;
        short8 bfr[4];
#pragma unroll
        for (int n = 0; n < 4; ++n)
          bfr[n] = *(const short8*)(bb + n * 512);

        const int f = 4 * sm + q;
#pragma unroll
        for (int mi = 0; mi < 2; ++mi) {
          const int rl = rl0 + mi * 16;
          const float hf = (LAYER == 1) ? bf16f(xs[rl * 40 + f])
                                        : bf16f(hs[f * HP + rl]);
          union { unsigned int u[4]; short8 s8; } A;
#pragma unroll
          for (int jj = 0; jj < 4; ++jj)
            A.u[jj] = pk2(hf * xw[mi][2 * jj], hf * xw[mi][2 * jj + 1]);
#pragma unroll
          for (int n = 0; n < 4; ++n)
            acc[mi][n] = __builtin_amdgcn_mfma_f32_16x16x32_bf16(
                A.s8, bfr[n], acc[mi][n], 0, 0, 0);
        }
      }
    }
  }
  asm volatile("s_waitcnt vmcnt(0)" ::: "memory");

  // ---- epilogue
  const int colb = tn * 64;
  float bv[4];
#pragma unroll
  for (int n = 0; n < 4; ++n) bv[n] = bias[colb + n * 16 + (l & 15)];

  if (LAYER == 3 || tn < 2) {
    const int jb = (LAYER == 1) ? 0 : (LAYER == 2) ? 128 : 256;
#pragma unroll
    for (int n = 0; n < 4; ++n) {
      const int j = jb + colb + n * 16 + (l & 15);
      float sum = 0.f;
#pragma unroll
      for (int m = 0; m < 2; ++m)
#pragma unroll
        for (int r = 0; r < 4; ++r) sum += fmaxf(acc[m][n][r] + bv[n], 0.f);
      sum += __shfl_xor(sum, 16);
      sum += __shfl_xor(sum, 32);
      if (l < 16) out[(b0 + wid) * 512 + j] = sum;
    }
  } else {
    // h half: cols 128..255 -> hOut[bm][f][rl], pitch 144
#pragma unroll
    for (int n = 0; n < 4; ++n) {
      const int ff = (tn - 2) * 64 + n * 16 + (l & 15);
#pragma unroll
      for (int m = 0; m < 2; ++m) {
        const int rl = wid * 32 + m * 16 + (l >> 4) * 4;
        float v0 = fmaxf(acc[m][n][0] + bv[n], 0.f);
        float v1 = fmaxf(acc[m][n][1] + bv[n], 0.f);
        float v2 = fmaxf(acc[m][n][2] + bv[n], 0.f);
        float v3 = fmaxf(acc[m][n][3] + bv[n], 0.f);
        uint2 pv;
        pv.x = pk2(v0, v1);
        pv.y = pk2(v2, v3);
        *(uint2*)&hOut[bm * (128 * HP) + ff * HP + rl] = pv;
      }
    }
  }
}

extern "C" void kernel_launch(void* const* d_in, const int* in_sizes, int n_in,
                              void* d_out, int out_size, void* d_ws, size_t ws_size,
                              hipStream_t stream) {
  (void)in_sizes; (void)n_in; (void)out_size; (void)ws_size;
  const float* in = (const float*)d_in[0];
  const float* W1 = (const float*)d_in[1];
  const float* b1 = (const float*)d_in[2];
  const float* W2 = (const float*)d_in[3];
  const float* b2 = (const float*)d_in[4];
  const float* W3 = (const float*)d_in[5];
  const float* b3 = (const float*)d_in[6];
  float* out = (float*)d_out;
  char* ws = (char*)d_ws;

  unsigned short* xT  = (unsigned short*)(ws);                 // 1,310,720 B
  unsigned short* Wf1 = (unsigned short*)(ws + 1310720);       //   819,200 B
  unsigned short* Wf2 = (unsigned short*)(ws + 2129920);       // 2,621,440 B
  unsigned short* Wf3 = (unsigned short*)(ws + 4751360);       // 2,621,440 B
  unsigned short* h1  = (unsigned short*)(ws + 7372800);       // 4,718,592 B
  unsigned short* h2  = (unsigned short*)(ws + 12091392);      // 4,718,592 B

  prep_x<<<dim3(512), dim3(256), 0, stream>>>(in, xT);
  prep_w<<<dim3(370), dim3(256), 0, stream>>>(W1, W2, W3, Wf1, Wf2, Wf3);
  cin_layer<1><<<dim3(512), dim3(256), 0, stream>>>(Wf1, xT, (const unsigned short*)nullptr, b1, h1, out);
  cin_layer<2><<<dim3(512), dim3(256), 0, stream>>>(Wf2, xT, h1, b2, h2, out);
  cin_layer<3><<<dim3(512), dim3(256), 0, stream>>>(Wf3, xT, h2, b3, (unsigned short*)nullptr, out);
}